// Round 10
// baseline (941.856 us; speedup 1.0000x reference)
//
#include <hip/hip_runtime.h>
#include <math.h>

#define NB 16
#define NF 768
#define NN 1024
#define KSEL 30

// ---------------- K1: per-(b,f) mean and 1/(std+1e-6) over the 1024 contiguous samples
__global__ __launch_bounds__(256) void k_stats(const float* __restrict__ data,
                                               double* __restrict__ meanv,
                                               double* __restrict__ invv) {
    int bf = blockIdx.x;
    int tid = threadIdx.x;
    const float4* p = reinterpret_cast<const float4*>(data + (size_t)bf * NN);
    float4 v = p[tid];
    double s  = (double)v.x + (double)v.y + (double)v.z + (double)v.w;
    double s2 = (double)v.x * (double)v.x + (double)v.y * (double)v.y +
                (double)v.z * (double)v.z + (double)v.w * (double)v.w;
    __shared__ double r1[256], r2[256];
    r1[tid] = s; r2[tid] = s2;
    __syncthreads();
    for (int st = 128; st > 0; st >>= 1) {
        if (tid < st) { r1[tid] += r1[tid + st]; r2[tid] += r2[tid + st]; }
        __syncthreads();
    }
    if (tid == 0) {
        double S = r1[0], S2 = r2[0];
        double mean = S / (double)NN;
        double var = (S2 - S * mean) / (double)(NN - 1);
        if (var < 0.0) var = 0.0;
        meanv[bf] = mean;
        invv[bf]  = 1.0 / (sqrt(var) + 1e-6);
    }
}

// ---------------- K2a: partial sq over f-chunks of 96 (512 blocks for parallelism)
__global__ __launch_bounds__(256) void k_sq1(const float* __restrict__ data,
                                             const double* __restrict__ meanv,
                                             const double* __restrict__ invv,
                                             double* __restrict__ psum) {
    int b = blockIdx.x >> 2;
    int n = ((blockIdx.x & 3) << 8) + threadIdx.x;
    int y = blockIdx.y;                 // f-chunk 0..7
    const float* base = data + (size_t)b * NF * NN;
    const double* mb = meanv + (size_t)b * NF;
    const double* ib = invv + (size_t)b * NF;
    double acc = 0.0;
    int f0 = y * 96;
    for (int f = f0; f < f0 + 96; ++f) {
        float x = base[(size_t)f * NN + n];
        float xn = (float)(((double)x - mb[f]) * ib[f]);
        acc = fma((double)xn, (double)xn, acc);
    }
    psum[((size_t)(b * 8 + y)) * NN + n] = acc;
}

// ---------------- K2b: reduce 8 partials -> sq[b,n]
__global__ __launch_bounds__(256) void k_sq2(const double* __restrict__ psum,
                                             double* __restrict__ sq) {
    int g = blockIdx.x * 256 + threadIdx.x;   // 0..16383
    int b = g >> 10, n = g & (NN - 1);
    double acc = 0.0;
    #pragma unroll
    for (int y = 0; y < 8; ++y) acc += psum[((size_t)(b * 8 + y)) * NN + n];
    sq[g] = acc;
}

// ---------------- K0: deg[n] = row-sum of adj (coalesced, one block per row)
__global__ __launch_bounds__(256) void k_deg(const float* __restrict__ adj, float* __restrict__ deg) {
    int n = blockIdx.x;
    int tid = threadIdx.x;
    const float4* row = reinterpret_cast<const float4*>(adj + (size_t)n * NN);
    float4 v = row[tid];
    float s = v.x + v.y + v.z + v.w;
    __shared__ float red[256];
    red[tid] = s; __syncthreads();
    for (int st = 128; st > 0; st >>= 1) {
        if (tid < st) red[tid] += red[tid + st];
        __syncthreads();
    }
    if (tid == 0) deg[n] = red[0];
}

// ---------------- K3: symmetric batched Gram + d2 epilogue (f64 accum)
// 128x128 tile, 256 threads, 8x8 per thread with 64 NAMED scalar accumulators
// (arrays + unroll provoked regalloc spills in rounds 2/7/8; named scalars
// remove every local array). Wave-quadrant mapping: wave -> 64x64 quadrant,
// lane -> (lane&7, lane>>3) 8x8 sub-tile => <=8 distinct 32B LDS addrs per
// read = 2-way bank aliasing (free, m136). Triangular pairs (36) + mirror.
__global__ __launch_bounds__(256) void k_gemm_sym(const float* __restrict__ data,
                                                  const double* __restrict__ meanv,
                                                  const double* __restrict__ invv,
                                                  const double* __restrict__ sq,
                                                  double* __restrict__ d2buf, int b0) {
    __shared__ float As[16][128];
    __shared__ float Bs[16][128];
    int tid = threadIdx.x;
    int lane = tid & 63, wave = tid >> 6;
    int wr = (wave & 1) * 64, wc = (wave >> 1) * 64;
    int lr = (lane & 7) * 8, lc = (lane >> 3) * 8;
    // triangular decode over 8x8 tiles of 128: t in [0,36), ti <= tj
    int t = blockIdx.x;
    int ti = 0, rem = t;
    while (rem >= 8 - ti) { rem -= 8 - ti; ++ti; }
    int tj = ti + rem;
    int n0 = ti * 128, m0 = tj * 128;
    int bb = blockIdx.z;
    int b = b0 + bb;
    const float* base = data + (size_t)b * NF * NN;
    const double* mb = meanv + (size_t)b * NF;
    const double* ib = invv + (size_t)b * NF;

    double c00=0,c01=0,c02=0,c03=0,c04=0,c05=0,c06=0,c07=0;
    double c10=0,c11=0,c12=0,c13=0,c14=0,c15=0,c16=0,c17=0;
    double c20=0,c21=0,c22=0,c23=0,c24=0,c25=0,c26=0,c27=0;
    double c30=0,c31=0,c32=0,c33=0,c34=0,c35=0,c36=0,c37=0;
    double c40=0,c41=0,c42=0,c43=0,c44=0,c45=0,c46=0,c47=0;
    double c50=0,c51=0,c52=0,c53=0,c54=0,c55=0,c56=0,c57=0;
    double c60=0,c61=0,c62=0,c63=0,c64=0,c65=0,c66=0,c67=0;
    double c70=0,c71=0,c72=0,c73=0,c74=0,c75=0,c76=0,c77=0;

    for (int f0 = 0; f0 < NF; f0 += 16) {
        #pragma unroll
        for (int r = 0; r < 2; ++r) {
            int idx = r * 256 + tid;   // 0..511 float4 slots (16 rows x 32)
            int k = idx >> 5, c4 = idx & 31;
            double mk = mb[f0 + k], ik = ib[f0 + k];
            float4 a = reinterpret_cast<const float4*>(base + (size_t)(f0 + k) * NN + n0)[c4];
            float4 c = reinterpret_cast<const float4*>(base + (size_t)(f0 + k) * NN + m0)[c4];
            float4 an, cn;
            an.x = (float)(((double)a.x - mk) * ik);
            an.y = (float)(((double)a.y - mk) * ik);
            an.z = (float)(((double)a.z - mk) * ik);
            an.w = (float)(((double)a.w - mk) * ik);
            cn.x = (float)(((double)c.x - mk) * ik);
            cn.y = (float)(((double)c.y - mk) * ik);
            cn.z = (float)(((double)c.z - mk) * ik);
            cn.w = (float)(((double)c.w - mk) * ik);
            reinterpret_cast<float4*>(&As[k][0])[c4] = an;
            reinterpret_cast<float4*>(&Bs[k][0])[c4] = cn;
        }
        __syncthreads();
        #pragma unroll 2
        for (int k = 0; k < 16; ++k) {
            float4 A0 = *reinterpret_cast<const float4*>(&As[k][wr + lr]);
            float4 A1 = *reinterpret_cast<const float4*>(&As[k][wr + lr + 4]);
            float4 B0 = *reinterpret_cast<const float4*>(&Bs[k][wc + lc]);
            float4 B1 = *reinterpret_cast<const float4*>(&Bs[k][wc + lc + 4]);
            double da0 = A0.x, da1 = A0.y, da2 = A0.z, da3 = A0.w;
            double da4 = A1.x, da5 = A1.y, da6 = A1.z, da7 = A1.w;
            double db0 = B0.x, db1 = B0.y, db2 = B0.z, db3 = B0.w;
            double db4 = B1.x, db5 = B1.y, db6 = B1.z, db7 = B1.w;
            #define FM(i)                                                   \
                c##i##0 = fma(da##i, db0, c##i##0);                         \
                c##i##1 = fma(da##i, db1, c##i##1);                         \
                c##i##2 = fma(da##i, db2, c##i##2);                         \
                c##i##3 = fma(da##i, db3, c##i##3);                         \
                c##i##4 = fma(da##i, db4, c##i##4);                         \
                c##i##5 = fma(da##i, db5, c##i##5);                         \
                c##i##6 = fma(da##i, db6, c##i##6);                         \
                c##i##7 = fma(da##i, db7, c##i##7);
            FM(0) FM(1) FM(2) FM(3) FM(4) FM(5) FM(6) FM(7)
            #undef FM
        }
        __syncthreads();
    }

    const double* sqb = sq + (size_t)b * NN;
    bool mirror = (ti != tj);
    #define WR1(i, j)                                                       \
        {                                                                   \
            int m = m0 + wc + lc + (j);                                     \
            double dd = sn + sqb[m] - 2.0 * c##i##j;                        \
            if (dd < 0.0) dd = 0.0;                                         \
            d2buf[rowbase + m] = dd;                                        \
            if (mirror) d2buf[((size_t)bb * NN + m) * NN + n] = dd;         \
        }
    #define WROW(i)                                                         \
        {                                                                   \
            int n = n0 + wr + lr + (i);                                     \
            double sn = sqb[n];                                             \
            size_t rowbase = ((size_t)bb * NN + n) * NN;                    \
            WR1(i,0) WR1(i,1) WR1(i,2) WR1(i,3)                             \
            WR1(i,4) WR1(i,5) WR1(i,6) WR1(i,7)                             \
        }
    WROW(0) WROW(1) WROW(2) WROW(3) WROW(4) WROW(5) WROW(6) WROW(7)
    #undef WROW
    #undef WR1
}

// ---------------- K4: per-row 31st smallest (index KSEL of ascending sort, diag included)
__global__ __launch_bounds__(256) void k_select(const double* __restrict__ d2buf,
                                                double* __restrict__ sel, int b0) {
    int rowc = blockIdx.x * 4 + (threadIdx.x >> 6);  // row within chunk
    int lane = threadIdx.x & 63;
    const double* r = d2buf + (size_t)rowc * NN;
    double v[16];
    #pragma unroll
    for (int s = 0; s < 16; ++s) v[s] = r[s * 64 + lane];
    double kth = 0.0;
    for (int t = 0; t <= KSEL; ++t) {
        double mv = v[0]; int ms = 0;
        #pragma unroll
        for (int s = 1; s < 16; ++s) { if (v[s] < mv) { mv = v[s]; ms = s; } }
        int mid = ms * 64 + lane;
        #pragma unroll
        for (int off = 1; off < 64; off <<= 1) {
            double ov = __shfl_xor(mv, off);
            int oid  = __shfl_xor(mid, off);
            if (ov < mv || (ov == mv && oid < mid)) { mv = ov; mid = oid; }
        }
        kth = mv;
        if (t < KSEL) {
            #pragma unroll
            for (int s = 0; s < 16; ++s) {
                if (s * 64 + lane == mid) v[s] = 1e300;
            }
        }
    }
    if (lane == 0) sel[(size_t)b0 * NN + rowc] = sqrt(kth);
}

// ---------------- K5: R2[b] = (mean_n sel)^2
__global__ __launch_bounds__(256) void k_R(const double* __restrict__ sel,
                                           double* __restrict__ R2v, int b0) {
    int b = b0 + blockIdx.x;
    int tid = threadIdx.x;
    const double* s = sel + (size_t)b * NN;
    double acc = s[tid] + s[tid + 256] + s[tid + 512] + s[tid + 768];
    __shared__ double red[256];
    red[tid] = acc; __syncthreads();
    for (int st = 128; st > 0; st >>= 1) {
        if (tid < st) red[tid] += red[tid + st];
        __syncthreads();
    }
    if (tid == 0) { double R = red[0] / (double)NN; R2v[b] = R * R; }
}

// ---------------- K6: per-row counts (samples: d2<R2, neighbors: adj&&d2>0&&d2<R2)
__global__ __launch_bounds__(256) void k_counts(const double* __restrict__ d2buf,
                                                const float* __restrict__ adj,
                                                const double* __restrict__ R2v,
                                                int* __restrict__ samplesN,
                                                int* __restrict__ neighborN,
                                                int* __restrict__ ssum, int b0) {
    int rowc = blockIdx.x;
    int g = b0 * NN + rowc;
    int b = g >> 10;
    int n = g & (NN - 1);
    double R2 = R2v[b];
    const double* r = d2buf + (size_t)rowc * NN;
    const float* arow = adj + (size_t)n * NN;
    int tid = threadIdx.x;
    int cs = 0, cn = 0;
    for (int i = tid; i < NN; i += 256) {
        double d = r[i];
        int lt = (d < R2) ? 1 : 0;
        cs += lt;
        float a = arow[i];
        if (a != 0.0f && d > 0.0 && lt) cn++;
    }
    __shared__ int rs[256], rn[256];
    rs[tid] = cs; rn[tid] = cn; __syncthreads();
    for (int st = 128; st > 0; st >>= 1) {
        if (tid < st) { rs[tid] += rs[tid + st]; rn[tid] += rn[tid + st]; }
        __syncthreads();
    }
    if (tid == 0) {
        samplesN[g]  = rs[0];
        neighborN[g] = rn[0];
        atomicAdd(&ssum[b], rs[0]);
    }
}

// ---------------- K7: fp32 scores, exact reference op order
__global__ __launch_bounds__(256) void k_score(const int* __restrict__ samplesN,
                                               const int* __restrict__ neighborN,
                                               const int* __restrict__ ssum,
                                               const float* __restrict__ deg,
                                               float* __restrict__ scoreb,
                                               float* __restrict__ outScore) {
    int g = blockIdx.x * 256 + threadIdx.x;
    int b = g >> 10, n = g & (NN - 1);
    float s  = (float)samplesN[g];
    float nb = (float)neighborN[g];
    float means = (float)ssum[b] / 1024.0f;
    float spatial  = nb / deg[n];
    float temporal = s / (s + means);
    float sc = (2.0f - spatial) - temporal;
    scoreb[g] = sc;
    outScore[g] = sc;
}

// ---------------- K8: stable double-argsort rank + keep mask
__global__ __launch_bounds__(1024) void k_rank(const float* __restrict__ scoreb,
                                               const float* __restrict__ pptr,
                                               float* __restrict__ keepf) {
    int b = blockIdx.x;
    int i = threadIdx.x;
    __shared__ float s[NN];
    s[i] = scoreb[b * NN + i];
    __syncthreads();
    float si = s[i];
    int rank = 0;
    for (int j = 0; j < NN; ++j) {
        float sj = s[j];
        if (sj < si || (sj == si && j < i)) rank++;
    }
    float cut = (float)NN * pptr[0];
    keepf[b * NN + i] = ((float)rank < cut) ? 1.0f : 0.0f;
}

// ---------------- K9: out = data * keep (broadcast over C,H)
__global__ __launch_bounds__(256) void k_apply(const float* __restrict__ data,
                                               const float* __restrict__ keepf,
                                               float* __restrict__ out) {
    size_t g4 = (size_t)blockIdx.x * 256 + threadIdx.x;
    size_t flat = g4 << 2;
    int w = (int)(flat & (NN - 1));
    int b = (int)(flat / ((size_t)NF * NN));
    float4 v = reinterpret_cast<const float4*>(data)[g4];
    const float4* kb = reinterpret_cast<const float4*>(keepf + b * NN + w);
    float4 kv = kb[0];
    float4 o;
    o.x = v.x * kv.x; o.y = v.y * kv.y; o.z = v.z * kv.z; o.w = v.w * kv.w;
    reinterpret_cast<float4*>(out)[g4] = o;
}

extern "C" void kernel_launch(void* const* d_in, const int* in_sizes, int n_in,
                              void* d_out, int out_size, void* d_ws, size_t ws_size,
                              hipStream_t stream) {
    const float* data = (const float*)d_in[0];
    const float* adj  = (const float*)d_in[1];
    const float* pptr = (const float*)d_in[4];
    float* out = (float*)d_out;
    float* outScore = out + (size_t)NB * NF * NN;

    char* w = (char*)d_ws;
    size_t off = 0;
    auto alloc = [&](size_t bytes) -> void* {
        off = (off + 255) & ~(size_t)255;
        void* p = w + off;
        off += bytes;
        return p;
    };
    double* meanv  = (double*)alloc((size_t)NB * NF * 8);
    double* invv   = (double*)alloc((size_t)NB * NF * 8);
    double* sq     = (double*)alloc((size_t)NB * NN * 8);
    double* psum   = (double*)alloc((size_t)NB * 8 * NN * 8);
    double* sel    = (double*)alloc((size_t)NB * NN * 8);
    double* R2v    = (double*)alloc((size_t)NB * 8);
    int* samplesN  = (int*)alloc((size_t)NB * NN * 4);
    int* neighborN = (int*)alloc((size_t)NB * NN * 4);
    int* ssum      = (int*)alloc((size_t)NB * 4);
    float* deg     = (float*)alloc((size_t)NN * 4);
    float* scoreb  = (float*)alloc((size_t)NB * NN * 4);
    float* keepf   = (float*)alloc((size_t)NB * NN * 4);
    off = (off + 255) & ~(size_t)255;
    size_t rem = (ws_size > off) ? (ws_size - off) : 0;
    int chunk = (int)(rem / ((size_t)NN * NN * 8));
    if (chunk > NB) chunk = NB;
    if (chunk < 1) chunk = 1;
    double* d2buf = (double*)(w + off);

    hipMemsetAsync(ssum, 0, NB * 4, stream);
    k_stats<<<NB * NF, 256, 0, stream>>>(data, meanv, invv);
    k_sq1<<<dim3(NB * 4, 8), 256, 0, stream>>>(data, meanv, invv, psum);
    k_sq2<<<NB * NN / 256, 256, 0, stream>>>(psum, sq);
    k_deg<<<NN, 256, 0, stream>>>(adj, deg);

    for (int b0 = 0; b0 < NB; b0 += chunk) {
        int c = (NB - b0 < chunk) ? (NB - b0) : chunk;
        dim3 gg(36, 1, c);
        k_gemm_sym<<<gg, 256, 0, stream>>>(data, meanv, invv, sq, d2buf, b0);
        k_select<<<c * NN / 4, 256, 0, stream>>>(d2buf, sel, b0);
        k_R<<<c, 256, 0, stream>>>(sel, R2v, b0);
        k_counts<<<c * NN, 256, 0, stream>>>(d2buf, adj, R2v, samplesN, neighborN, ssum, b0);
    }

    k_score<<<NB * NN / 256, 256, 0, stream>>>(samplesN, neighborN, ssum, deg, scoreb, outScore);
    k_rank<<<NB, 1024, 0, stream>>>(scoreb, pptr, keepf);
    k_apply<<<(NB * NF * NN) / (256 * 4), 256, 0, stream>>>(data, keepf, out);
}

// Round 11
// 794.600 us; speedup vs baseline: 1.1853x; 1.1853x over previous
//
#include <hip/hip_runtime.h>
#include <math.h>

#define NB 16
#define NF 768
#define NN 1024
#define KSEL 30

// ---------------- K1: per-(b,f) mean and 1/(std+1e-6); one wave per row
__global__ __launch_bounds__(256) void k_stats(const float* __restrict__ data,
                                               double* __restrict__ meanv,
                                               double* __restrict__ invv) {
    int bf = blockIdx.x * 4 + (threadIdx.x >> 6);
    int lane = threadIdx.x & 63;
    const float4* p = reinterpret_cast<const float4*>(data + (size_t)bf * NN);
    double s = 0.0, s2 = 0.0;
    #pragma unroll
    for (int r = 0; r < 4; ++r) {
        float4 v = p[r * 64 + lane];
        s  += (double)v.x + (double)v.y + (double)v.z + (double)v.w;
        s2 += (double)v.x * (double)v.x + (double)v.y * (double)v.y +
              (double)v.z * (double)v.z + (double)v.w * (double)v.w;
    }
    #pragma unroll
    for (int off = 1; off < 64; off <<= 1) {
        s  += __shfl_xor(s, off);
        s2 += __shfl_xor(s2, off);
    }
    if (lane == 0) {
        double mean = s / (double)NN;
        double var = (s2 - s * mean) / (double)(NN - 1);
        if (var < 0.0) var = 0.0;
        meanv[bf] = mean;
        invv[bf]  = 1.0 / (sqrt(var) + 1e-6);
    }
}

// ---------------- K2a: partial sq over f-chunks of 96 (512 blocks for parallelism)
__global__ __launch_bounds__(256) void k_sq1(const float* __restrict__ data,
                                             const double* __restrict__ meanv,
                                             const double* __restrict__ invv,
                                             double* __restrict__ psum) {
    int b = blockIdx.x >> 2;
    int n = ((blockIdx.x & 3) << 8) + threadIdx.x;
    int y = blockIdx.y;                 // f-chunk 0..7
    const float* base = data + (size_t)b * NF * NN;
    const double* mb = meanv + (size_t)b * NF;
    const double* ib = invv + (size_t)b * NF;
    double acc = 0.0;
    int f0 = y * 96;
    for (int f = f0; f < f0 + 96; ++f) {
        float x = base[(size_t)f * NN + n];
        float xn = (float)(((double)x - mb[f]) * ib[f]);
        acc = fma((double)xn, (double)xn, acc);
    }
    psum[((size_t)(b * 8 + y)) * NN + n] = acc;
}

// ---------------- K2b: reduce 8 partials -> sq[b,n]
__global__ __launch_bounds__(256) void k_sq2(const double* __restrict__ psum,
                                             double* __restrict__ sq) {
    int g = blockIdx.x * 256 + threadIdx.x;   // 0..16383
    int b = g >> 10, n = g & (NN - 1);
    double acc = 0.0;
    #pragma unroll
    for (int y = 0; y < 8; ++y) acc += psum[((size_t)(b * 8 + y)) * NN + n];
    sq[g] = acc;
}

// ---------------- K0: deg[n] = row-sum of adj; one wave per row (counts -> order-exact)
__global__ __launch_bounds__(256) void k_deg(const float* __restrict__ adj, float* __restrict__ deg) {
    int n = blockIdx.x * 4 + (threadIdx.x >> 6);
    int lane = threadIdx.x & 63;
    const float4* row = reinterpret_cast<const float4*>(adj + (size_t)n * NN);
    float s = 0.0f;
    #pragma unroll
    for (int r = 0; r < 4; ++r) {
        float4 v = row[r * 64 + lane];
        s += v.x + v.y + v.z + v.w;
    }
    #pragma unroll
    for (int off = 1; off < 64; off <<= 1) s += __shfl_xor(s, off);
    if (lane == 0) deg[n] = s;
}

// ---------------- K3: symmetric batched Gram + d2 epilogue (f64 accum)
// Round-9 proven structure (64x64 tiles, 4x4 acc, 136 triangular pairs) with
// f64 LDS staging: the 8 v_cvt_f64_f32 per k-step (~20-25% of inner-loop
// VALU issue) move to staging (8 cvt per 32 k-steps). Stored values are
// (double)(float)(...) == exactly the f32-rounded quantities -> bitwise-
// identical d2 vs round 9. LDS 32KB -> >=5 blocks/CU, no occupancy loss.
__global__ __launch_bounds__(256) void k_gemm_sym(const float* __restrict__ data,
                                                  const double* __restrict__ meanv,
                                                  const double* __restrict__ invv,
                                                  const double* __restrict__ sq,
                                                  double* __restrict__ d2buf, int b0) {
    __shared__ double As[32][64];
    __shared__ double Bs[32][64];
    int tid = threadIdx.x;
    int tx = tid & 15, ty = tid >> 4;
    // triangular decode over 16x16 tiles of 64: t in [0,136), ti <= tj
    int t = blockIdx.x;
    int ti = 0, rem = t;
    while (rem >= 16 - ti) { rem -= 16 - ti; ++ti; }
    int tj = ti + rem;
    int n0 = ti * 64, m0 = tj * 64;
    int bb = blockIdx.z;
    int b = b0 + bb;
    const float* base = data + (size_t)b * NF * NN;
    const double* mb = meanv + (size_t)b * NF;
    const double* ib = invv + (size_t)b * NF;
    double acc[4][4] = {{0.0}};
    for (int f0 = 0; f0 < NF; f0 += 32) {
        #pragma unroll
        for (int r = 0; r < 2; ++r) {
            int idx = r * 256 + tid;   // 0..511 float4 slots (32 rows x 16)
            int k = idx >> 4;
            int j4 = idx & 15;
            double mk = mb[f0 + k], ik = ib[f0 + k];
            const float4* pa = reinterpret_cast<const float4*>(base + (size_t)(f0 + k) * NN + n0);
            const float4* pb = reinterpret_cast<const float4*>(base + (size_t)(f0 + k) * NN + m0);
            float4 a = pa[j4], c = pb[j4];
            As[k][j4 * 4 + 0] = (double)(float)(((double)a.x - mk) * ik);
            As[k][j4 * 4 + 1] = (double)(float)(((double)a.y - mk) * ik);
            As[k][j4 * 4 + 2] = (double)(float)(((double)a.z - mk) * ik);
            As[k][j4 * 4 + 3] = (double)(float)(((double)a.w - mk) * ik);
            Bs[k][j4 * 4 + 0] = (double)(float)(((double)c.x - mk) * ik);
            Bs[k][j4 * 4 + 1] = (double)(float)(((double)c.y - mk) * ik);
            Bs[k][j4 * 4 + 2] = (double)(float)(((double)c.z - mk) * ik);
            Bs[k][j4 * 4 + 3] = (double)(float)(((double)c.w - mk) * ik);
        }
        __syncthreads();
        #pragma unroll 8
        for (int k = 0; k < 32; ++k) {
            double2 a01 = *reinterpret_cast<const double2*>(&As[k][tx * 4]);
            double2 a23 = *reinterpret_cast<const double2*>(&As[k][tx * 4 + 2]);
            double2 b01 = *reinterpret_cast<const double2*>(&Bs[k][ty * 4]);
            double2 b23 = *reinterpret_cast<const double2*>(&Bs[k][ty * 4 + 2]);
            double a0 = a01.x, a1 = a01.y, a2 = a23.x, a3 = a23.y;
            double b0d = b01.x, b1d = b01.y, b2d = b23.x, b3d = b23.y;
            acc[0][0] = fma(a0, b0d, acc[0][0]);
            acc[0][1] = fma(a0, b1d, acc[0][1]);
            acc[0][2] = fma(a0, b2d, acc[0][2]);
            acc[0][3] = fma(a0, b3d, acc[0][3]);
            acc[1][0] = fma(a1, b0d, acc[1][0]);
            acc[1][1] = fma(a1, b1d, acc[1][1]);
            acc[1][2] = fma(a1, b2d, acc[1][2]);
            acc[1][3] = fma(a1, b3d, acc[1][3]);
            acc[2][0] = fma(a2, b0d, acc[2][0]);
            acc[2][1] = fma(a2, b1d, acc[2][1]);
            acc[2][2] = fma(a2, b2d, acc[2][2]);
            acc[2][3] = fma(a2, b3d, acc[2][3]);
            acc[3][0] = fma(a3, b0d, acc[3][0]);
            acc[3][1] = fma(a3, b1d, acc[3][1]);
            acc[3][2] = fma(a3, b2d, acc[3][2]);
            acc[3][3] = fma(a3, b3d, acc[3][3]);
        }
        __syncthreads();
    }
    const double* sqb = sq + (size_t)b * NN;
    bool mirror = (ti != tj);
    #pragma unroll
    for (int i = 0; i < 4; ++i) {
        int n = n0 + tx * 4 + i;
        double sn = sqb[n];
        #pragma unroll
        for (int j = 0; j < 4; ++j) {
            int m = m0 + ty * 4 + j;
            double d2 = sn + sqb[m] - 2.0 * acc[i][j];
            if (d2 < 0.0) d2 = 0.0;
            d2buf[((size_t)bb * NN + n) * NN + m] = d2;
            if (mirror) d2buf[((size_t)bb * NN + m) * NN + n] = d2;
        }
    }
}

// ---------------- K4: per-row 31st smallest (index KSEL of ascending sort, diag included)
__global__ __launch_bounds__(256) void k_select(const double* __restrict__ d2buf,
                                                double* __restrict__ sel, int b0) {
    int rowc = blockIdx.x * 4 + (threadIdx.x >> 6);  // row within chunk
    int lane = threadIdx.x & 63;
    const double* r = d2buf + (size_t)rowc * NN;
    double v[16];
    #pragma unroll
    for (int s = 0; s < 16; ++s) v[s] = r[s * 64 + lane];
    double kth = 0.0;
    for (int t = 0; t <= KSEL; ++t) {
        double mv = v[0]; int ms = 0;
        #pragma unroll
        for (int s = 1; s < 16; ++s) { if (v[s] < mv) { mv = v[s]; ms = s; } }
        int mid = ms * 64 + lane;
        #pragma unroll
        for (int off = 1; off < 64; off <<= 1) {
            double ov = __shfl_xor(mv, off);
            int oid  = __shfl_xor(mid, off);
            if (ov < mv || (ov == mv && oid < mid)) { mv = ov; mid = oid; }
        }
        kth = mv;
        if (t < KSEL) {
            #pragma unroll
            for (int s = 0; s < 16; ++s) {
                if (s * 64 + lane == mid) v[s] = 1e300;
            }
        }
    }
    if (lane == 0) sel[(size_t)b0 * NN + rowc] = sqrt(kth);
}

// ---------------- K5: R2[b] = (mean_n sel)^2
__global__ __launch_bounds__(256) void k_R(const double* __restrict__ sel,
                                           double* __restrict__ R2v, int b0) {
    int b = b0 + blockIdx.x;
    int tid = threadIdx.x;
    const double* s = sel + (size_t)b * NN;
    double acc = s[tid] + s[tid + 256] + s[tid + 512] + s[tid + 768];
    __shared__ double red[256];
    red[tid] = acc; __syncthreads();
    for (int st = 128; st > 0; st >>= 1) {
        if (tid < st) red[tid] += red[tid + st];
        __syncthreads();
    }
    if (tid == 0) { double R = red[0] / (double)NN; R2v[b] = R * R; }
}

// ---------------- K6: per-row counts (samples: d2<R2, neighbors: adj&&d2>0&&d2<R2)
__global__ __launch_bounds__(256) void k_counts(const double* __restrict__ d2buf,
                                                const float* __restrict__ adj,
                                                const double* __restrict__ R2v,
                                                int* __restrict__ samplesN,
                                                int* __restrict__ neighborN,
                                                int* __restrict__ ssum, int b0) {
    int rowc = blockIdx.x;
    int g = b0 * NN + rowc;
    int b = g >> 10;
    int n = g & (NN - 1);
    double R2 = R2v[b];
    const double* r = d2buf + (size_t)rowc * NN;
    const float* arow = adj + (size_t)n * NN;
    int tid = threadIdx.x;
    int cs = 0, cn = 0;
    for (int i = tid; i < NN; i += 256) {
        double d = r[i];
        int lt = (d < R2) ? 1 : 0;
        cs += lt;
        float a = arow[i];
        if (a != 0.0f && d > 0.0 && lt) cn++;
    }
    __shared__ int rs[256], rn[256];
    rs[tid] = cs; rn[tid] = cn; __syncthreads();
    for (int st = 128; st > 0; st >>= 1) {
        if (tid < st) { rs[tid] += rs[tid + st]; rn[tid] += rn[tid + st]; }
        __syncthreads();
    }
    if (tid == 0) {
        samplesN[g]  = rs[0];
        neighborN[g] = rn[0];
        atomicAdd(&ssum[b], rs[0]);
    }
}

// ---------------- K8: fused score + stable double-argsort rank + keep mask
__global__ __launch_bounds__(1024) void k_rank(const int* __restrict__ samplesN,
                                               const int* __restrict__ neighborN,
                                               const int* __restrict__ ssum,
                                               const float* __restrict__ deg,
                                               const float* __restrict__ pptr,
                                               float* __restrict__ keepf,
                                               float* __restrict__ outScore) {
    int b = blockIdx.x;
    int i = threadIdx.x;
    int g = b * NN + i;
    float sv  = (float)samplesN[g];
    float nb  = (float)neighborN[g];
    float means = (float)ssum[b] / 1024.0f;
    float spatial  = nb / deg[i];
    float temporal = sv / (sv + means);
    float sc = (2.0f - spatial) - temporal;
    outScore[g] = sc;
    __shared__ float s[NN];
    s[i] = sc;
    __syncthreads();
    float si = s[i];
    int rank = 0;
    for (int j = 0; j < NN; ++j) {
        float sj = s[j];
        if (sj < si || (sj == si && j < i)) rank++;
    }
    float cut = (float)NN * pptr[0];
    keepf[g] = ((float)rank < cut) ? 1.0f : 0.0f;
}

// ---------------- K9: out = data * keep (broadcast over C,H)
__global__ __launch_bounds__(256) void k_apply(const float* __restrict__ data,
                                               const float* __restrict__ keepf,
                                               float* __restrict__ out) {
    size_t g4 = (size_t)blockIdx.x * 256 + threadIdx.x;
    size_t flat = g4 << 2;
    int w = (int)(flat & (NN - 1));
    int b = (int)(flat / ((size_t)NF * NN));
    float4 v = reinterpret_cast<const float4*>(data)[g4];
    const float4* kb = reinterpret_cast<const float4*>(keepf + b * NN + w);
    float4 kv = kb[0];
    float4 o;
    o.x = v.x * kv.x; o.y = v.y * kv.y; o.z = v.z * kv.z; o.w = v.w * kv.w;
    reinterpret_cast<float4*>(out)[g4] = o;
}

extern "C" void kernel_launch(void* const* d_in, const int* in_sizes, int n_in,
                              void* d_out, int out_size, void* d_ws, size_t ws_size,
                              hipStream_t stream) {
    const float* data = (const float*)d_in[0];
    const float* adj  = (const float*)d_in[1];
    const float* pptr = (const float*)d_in[4];
    float* out = (float*)d_out;
    float* outScore = out + (size_t)NB * NF * NN;

    char* w = (char*)d_ws;
    size_t off = 0;
    auto alloc = [&](size_t bytes) -> void* {
        off = (off + 255) & ~(size_t)255;
        void* p = w + off;
        off += bytes;
        return p;
    };
    double* meanv  = (double*)alloc((size_t)NB * NF * 8);
    double* invv   = (double*)alloc((size_t)NB * NF * 8);
    double* sq     = (double*)alloc((size_t)NB * NN * 8);
    double* psum   = (double*)alloc((size_t)NB * 8 * NN * 8);
    double* sel    = (double*)alloc((size_t)NB * NN * 8);
    double* R2v    = (double*)alloc((size_t)NB * 8);
    int* samplesN  = (int*)alloc((size_t)NB * NN * 4);
    int* neighborN = (int*)alloc((size_t)NB * NN * 4);
    int* ssum      = (int*)alloc((size_t)NB * 4);
    float* deg     = (float*)alloc((size_t)NN * 4);
    float* keepf   = (float*)alloc((size_t)NB * NN * 4);
    off = (off + 255) & ~(size_t)255;
    size_t rem = (ws_size > off) ? (ws_size - off) : 0;
    int chunk = (int)(rem / ((size_t)NN * NN * 8));
    if (chunk > NB) chunk = NB;
    if (chunk < 1) chunk = 1;
    double* d2buf = (double*)(w + off);

    hipMemsetAsync(ssum, 0, NB * 4, stream);
    k_stats<<<NB * NF / 4, 256, 0, stream>>>(data, meanv, invv);
    k_sq1<<<dim3(NB * 4, 8), 256, 0, stream>>>(data, meanv, invv, psum);
    k_sq2<<<NB * NN / 256, 256, 0, stream>>>(psum, sq);
    k_deg<<<NN / 4, 256, 0, stream>>>(adj, deg);

    for (int b0 = 0; b0 < NB; b0 += chunk) {
        int c = (NB - b0 < chunk) ? (NB - b0) : chunk;
        dim3 gg(136, 1, c);
        k_gemm_sym<<<gg, 256, 0, stream>>>(data, meanv, invv, sq, d2buf, b0);
        k_select<<<c * NN / 4, 256, 0, stream>>>(d2buf, sel, b0);
        k_R<<<c, 256, 0, stream>>>(sel, R2v, b0);
        k_counts<<<c * NN, 256, 0, stream>>>(d2buf, adj, R2v, samplesN, neighborN, ssum, b0);
    }

    k_rank<<<NB, 1024, 0, stream>>>(samplesN, neighborN, ssum, deg, pptr, keepf, outScore);
    k_apply<<<(NB * NF * NN) / (256 * 4), 256, 0, stream>>>(data, keepf, out);
}

// Round 12
// 741.721 us; speedup vs baseline: 1.2698x; 1.0713x over previous
//
#include <hip/hip_runtime.h>
#include <math.h>

#define NB 16
#define NF 768
#define NN 1024
#define KSEL 30

// ---------------- K1: per-(b,f) mean and 1/(std+1e-6); one wave per row
__global__ __launch_bounds__(256) void k_stats(const float* __restrict__ data,
                                               double* __restrict__ meanv,
                                               double* __restrict__ invv) {
    int bf = blockIdx.x * 4 + (threadIdx.x >> 6);
    int lane = threadIdx.x & 63;
    const float4* p = reinterpret_cast<const float4*>(data + (size_t)bf * NN);
    double s = 0.0, s2 = 0.0;
    #pragma unroll
    for (int r = 0; r < 4; ++r) {
        float4 v = p[r * 64 + lane];
        s  += (double)v.x + (double)v.y + (double)v.z + (double)v.w;
        s2 += (double)v.x * (double)v.x + (double)v.y * (double)v.y +
              (double)v.z * (double)v.z + (double)v.w * (double)v.w;
    }
    #pragma unroll
    for (int off = 1; off < 64; off <<= 1) {
        s  += __shfl_xor(s, off);
        s2 += __shfl_xor(s2, off);
    }
    if (lane == 0) {
        double mean = s / (double)NN;
        double var = (s2 - s * mean) / (double)(NN - 1);
        if (var < 0.0) var = 0.0;
        meanv[bf] = mean;
        invv[bf]  = 1.0 / (sqrt(var) + 1e-6);
    }
}

// ---------------- K2a: partial sq over f-chunks of 96 (512 blocks for parallelism)
__global__ __launch_bounds__(256) void k_sq1(const float* __restrict__ data,
                                             const double* __restrict__ meanv,
                                             const double* __restrict__ invv,
                                             double* __restrict__ psum) {
    int b = blockIdx.x >> 2;
    int n = ((blockIdx.x & 3) << 8) + threadIdx.x;
    int y = blockIdx.y;                 // f-chunk 0..7
    const float* base = data + (size_t)b * NF * NN;
    const double* mb = meanv + (size_t)b * NF;
    const double* ib = invv + (size_t)b * NF;
    double acc = 0.0;
    int f0 = y * 96;
    for (int f = f0; f < f0 + 96; ++f) {
        float x = base[(size_t)f * NN + n];
        float xn = (float)(((double)x - mb[f]) * ib[f]);
        acc = fma((double)xn, (double)xn, acc);
    }
    psum[((size_t)(b * 8 + y)) * NN + n] = acc;
}

// ---------------- K2b: reduce 8 partials -> sq[b,n]
__global__ __launch_bounds__(256) void k_sq2(const double* __restrict__ psum,
                                             double* __restrict__ sq) {
    int g = blockIdx.x * 256 + threadIdx.x;   // 0..16383
    int b = g >> 10, n = g & (NN - 1);
    double acc = 0.0;
    #pragma unroll
    for (int y = 0; y < 8; ++y) acc += psum[((size_t)(b * 8 + y)) * NN + n];
    sq[g] = acc;
}

// ---------------- K0: deg[n] = row-sum of adj; one wave per row
__global__ __launch_bounds__(256) void k_deg(const float* __restrict__ adj, float* __restrict__ deg) {
    int n = blockIdx.x * 4 + (threadIdx.x >> 6);
    int lane = threadIdx.x & 63;
    const float4* row = reinterpret_cast<const float4*>(adj + (size_t)n * NN);
    float s = 0.0f;
    #pragma unroll
    for (int r = 0; r < 4; ++r) {
        float4 v = row[r * 64 + lane];
        s += v.x + v.y + v.z + v.w;
    }
    #pragma unroll
    for (int off = 1; off < 64; off <<= 1) s += __shfl_xor(s, off);
    if (lane == 0) deg[n] = s;
}

// ---------------- K3: symmetric batched Gram + d2 epilogue (f64 accum)
// f64 LDS (cvt-free inner loop) with CONFLICT-FREE access patterns:
//  - fragment read: two double2 per operand at 16B stride -> 16 addrs x 16B
//    contiguous = 2-way bank aliasing = free (round-11's 32B-stride double2
//    pattern was 4-way -> 6.7e7 conflict cycles).
//  - staging: float2 global loads -> double2 LDS writes at 16B stride (2-way).
// Fragment cols: A = {tx*2, tx*2+1, tx*2+32, tx*2+33}; B same with ty.
// Same k-order per (n,m) dot product -> bitwise-identical d2 vs rounds 9/11.
__global__ __launch_bounds__(256) void k_gemm_sym(const float* __restrict__ data,
                                                  const double* __restrict__ meanv,
                                                  const double* __restrict__ invv,
                                                  const double* __restrict__ sq,
                                                  double* __restrict__ d2buf, int b0) {
    __shared__ double As[32][64];
    __shared__ double Bs[32][64];
    int tid = threadIdx.x;
    int tx = tid & 15, ty = tid >> 4;
    // triangular decode over 16x16 tiles of 64: t in [0,136), ti <= tj
    int t = blockIdx.x;
    int ti = 0, rem = t;
    while (rem >= 16 - ti) { rem -= 16 - ti; ++ti; }
    int tj = ti + rem;
    int n0 = ti * 64, m0 = tj * 64;
    int bb = blockIdx.z;
    int b = b0 + bb;
    const float* base = data + (size_t)b * NF * NN;
    const double* mb = meanv + (size_t)b * NF;
    const double* ib = invv + (size_t)b * NF;
    double acc[4][4] = {{0.0}};
    for (int f0 = 0; f0 < NF; f0 += 32) {
        // stage 32 k-rows x 64 cols: 1024 float2 slots, 4 per thread
        #pragma unroll
        for (int r = 0; r < 4; ++r) {
            int idx = r * 256 + tid;   // 0..1023
            int k = idx >> 5;          // 0..31
            int c2 = idx & 31;         // float2 col 0..31
            double mk = mb[f0 + k], ik = ib[f0 + k];
            float2 a = *reinterpret_cast<const float2*>(base + (size_t)(f0 + k) * NN + n0 + c2 * 2);
            float2 c = *reinterpret_cast<const float2*>(base + (size_t)(f0 + k) * NN + m0 + c2 * 2);
            double2 da, dc;
            da.x = (double)(float)(((double)a.x - mk) * ik);
            da.y = (double)(float)(((double)a.y - mk) * ik);
            dc.x = (double)(float)(((double)c.x - mk) * ik);
            dc.y = (double)(float)(((double)c.y - mk) * ik);
            *reinterpret_cast<double2*>(&As[k][c2 * 2]) = da;
            *reinterpret_cast<double2*>(&Bs[k][c2 * 2]) = dc;
        }
        __syncthreads();
        #pragma unroll 8
        for (int k = 0; k < 32; ++k) {
            double2 aL = *reinterpret_cast<const double2*>(&As[k][tx * 2]);
            double2 aH = *reinterpret_cast<const double2*>(&As[k][tx * 2 + 32]);
            double2 bL = *reinterpret_cast<const double2*>(&Bs[k][ty * 2]);
            double2 bH = *reinterpret_cast<const double2*>(&Bs[k][ty * 2 + 32]);
            double a0 = aL.x, a1 = aL.y, a2 = aH.x, a3 = aH.y;
            double b0d = bL.x, b1d = bL.y, b2d = bH.x, b3d = bH.y;
            acc[0][0] = fma(a0, b0d, acc[0][0]);
            acc[0][1] = fma(a0, b1d, acc[0][1]);
            acc[0][2] = fma(a0, b2d, acc[0][2]);
            acc[0][3] = fma(a0, b3d, acc[0][3]);
            acc[1][0] = fma(a1, b0d, acc[1][0]);
            acc[1][1] = fma(a1, b1d, acc[1][1]);
            acc[1][2] = fma(a1, b2d, acc[1][2]);
            acc[1][3] = fma(a1, b3d, acc[1][3]);
            acc[2][0] = fma(a2, b0d, acc[2][0]);
            acc[2][1] = fma(a2, b1d, acc[2][1]);
            acc[2][2] = fma(a2, b2d, acc[2][2]);
            acc[2][3] = fma(a2, b3d, acc[2][3]);
            acc[3][0] = fma(a3, b0d, acc[3][0]);
            acc[3][1] = fma(a3, b1d, acc[3][1]);
            acc[3][2] = fma(a3, b2d, acc[3][2]);
            acc[3][3] = fma(a3, b3d, acc[3][3]);
        }
        __syncthreads();
    }
    const double* sqb = sq + (size_t)b * NN;
    bool mirror = (ti != tj);
    #pragma unroll
    for (int i = 0; i < 4; ++i) {
        int n = n0 + ((i & 2) ? 32 : 0) + tx * 2 + (i & 1);
        double sn = sqb[n];
        #pragma unroll
        for (int j = 0; j < 4; ++j) {
            int m = m0 + ((j & 2) ? 32 : 0) + ty * 2 + (j & 1);
            double d2 = sn + sqb[m] - 2.0 * acc[i][j];
            if (d2 < 0.0) d2 = 0.0;
            d2buf[((size_t)bb * NN + n) * NN + m] = d2;
            if (mirror) d2buf[((size_t)bb * NN + m) * NN + n] = d2;
        }
    }
}

// ---------------- K4: per-row 31st smallest (index KSEL of ascending sort, diag included)
__global__ __launch_bounds__(256) void k_select(const double* __restrict__ d2buf,
                                                double* __restrict__ sel, int b0) {
    int rowc = blockIdx.x * 4 + (threadIdx.x >> 6);  // row within chunk
    int lane = threadIdx.x & 63;
    const double* r = d2buf + (size_t)rowc * NN;
    double v[16];
    #pragma unroll
    for (int s = 0; s < 16; ++s) v[s] = r[s * 64 + lane];
    double kth = 0.0;
    for (int t = 0; t <= KSEL; ++t) {
        double mv = v[0]; int ms = 0;
        #pragma unroll
        for (int s = 1; s < 16; ++s) { if (v[s] < mv) { mv = v[s]; ms = s; } }
        int mid = ms * 64 + lane;
        #pragma unroll
        for (int off = 1; off < 64; off <<= 1) {
            double ov = __shfl_xor(mv, off);
            int oid  = __shfl_xor(mid, off);
            if (ov < mv || (ov == mv && oid < mid)) { mv = ov; mid = oid; }
        }
        kth = mv;
        if (t < KSEL) {
            #pragma unroll
            for (int s = 0; s < 16; ++s) {
                if (s * 64 + lane == mid) v[s] = 1e300;
            }
        }
    }
    if (lane == 0) sel[(size_t)b0 * NN + rowc] = sqrt(kth);
}

// ---------------- K5: R2[b] = (mean_n sel)^2
__global__ __launch_bounds__(256) void k_R(const double* __restrict__ sel,
                                           double* __restrict__ R2v, int b0) {
    int b = b0 + blockIdx.x;
    int tid = threadIdx.x;
    const double* s = sel + (size_t)b * NN;
    double acc = s[tid] + s[tid + 256] + s[tid + 512] + s[tid + 768];
    __shared__ double red[256];
    red[tid] = acc; __syncthreads();
    for (int st = 128; st > 0; st >>= 1) {
        if (tid < st) red[tid] += red[tid + st];
        __syncthreads();
    }
    if (tid == 0) { double R = red[0] / (double)NN; R2v[b] = R * R; }
}

// ---------------- K6: per-row counts (samples: d2<R2, neighbors: adj&&d2>0&&d2<R2)
__global__ __launch_bounds__(256) void k_counts(const double* __restrict__ d2buf,
                                                const float* __restrict__ adj,
                                                const double* __restrict__ R2v,
                                                int* __restrict__ samplesN,
                                                int* __restrict__ neighborN,
                                                int* __restrict__ ssum, int b0) {
    int rowc = blockIdx.x;
    int g = b0 * NN + rowc;
    int b = g >> 10;
    int n = g & (NN - 1);
    double R2 = R2v[b];
    const double* r = d2buf + (size_t)rowc * NN;
    const float* arow = adj + (size_t)n * NN;
    int tid = threadIdx.x;
    int cs = 0, cn = 0;
    for (int i = tid; i < NN; i += 256) {
        double d = r[i];
        int lt = (d < R2) ? 1 : 0;
        cs += lt;
        float a = arow[i];
        if (a != 0.0f && d > 0.0 && lt) cn++;
    }
    __shared__ int rs[256], rn[256];
    rs[tid] = cs; rn[tid] = cn; __syncthreads();
    for (int st = 128; st > 0; st >>= 1) {
        if (tid < st) { rs[tid] += rs[tid + st]; rn[tid] += rn[tid + st]; }
        __syncthreads();
    }
    if (tid == 0) {
        samplesN[g]  = rs[0];
        neighborN[g] = rn[0];
        atomicAdd(&ssum[b], rs[0]);
    }
}

// ---------------- K8: fused score + stable double-argsort rank + keep mask
__global__ __launch_bounds__(1024) void k_rank(const int* __restrict__ samplesN,
                                               const int* __restrict__ neighborN,
                                               const int* __restrict__ ssum,
                                               const float* __restrict__ deg,
                                               const float* __restrict__ pptr,
                                               float* __restrict__ keepf,
                                               float* __restrict__ outScore) {
    int b = blockIdx.x;
    int i = threadIdx.x;
    int g = b * NN + i;
    float sv  = (float)samplesN[g];
    float nb  = (float)neighborN[g];
    float means = (float)ssum[b] / 1024.0f;
    float spatial  = nb / deg[i];
    float temporal = sv / (sv + means);
    float sc = (2.0f - spatial) - temporal;
    outScore[g] = sc;
    __shared__ float s[NN];
    s[i] = sc;
    __syncthreads();
    float si = s[i];
    int rank = 0;
    for (int j = 0; j < NN; ++j) {
        float sj = s[j];
        if (sj < si || (sj == si && j < i)) rank++;
    }
    float cut = (float)NN * pptr[0];
    keepf[g] = ((float)rank < cut) ? 1.0f : 0.0f;
}

// ---------------- K9: out = data * keep (broadcast over C,H)
__global__ __launch_bounds__(256) void k_apply(const float* __restrict__ data,
                                               const float* __restrict__ keepf,
                                               float* __restrict__ out) {
    size_t g4 = (size_t)blockIdx.x * 256 + threadIdx.x;
    size_t flat = g4 << 2;
    int w = (int)(flat & (NN - 1));
    int b = (int)(flat / ((size_t)NF * NN));
    float4 v = reinterpret_cast<const float4*>(data)[g4];
    const float4* kb = reinterpret_cast<const float4*>(keepf + b * NN + w);
    float4 kv = kb[0];
    float4 o;
    o.x = v.x * kv.x; o.y = v.y * kv.y; o.z = v.z * kv.z; o.w = v.w * kv.w;
    reinterpret_cast<float4*>(out)[g4] = o;
}

extern "C" void kernel_launch(void* const* d_in, const int* in_sizes, int n_in,
                              void* d_out, int out_size, void* d_ws, size_t ws_size,
                              hipStream_t stream) {
    const float* data = (const float*)d_in[0];
    const float* adj  = (const float*)d_in[1];
    const float* pptr = (const float*)d_in[4];
    float* out = (float*)d_out;
    float* outScore = out + (size_t)NB * NF * NN;

    char* w = (char*)d_ws;
    size_t off = 0;
    auto alloc = [&](size_t bytes) -> void* {
        off = (off + 255) & ~(size_t)255;
        void* p = w + off;
        off += bytes;
        return p;
    };
    double* meanv  = (double*)alloc((size_t)NB * NF * 8);
    double* invv   = (double*)alloc((size_t)NB * NF * 8);
    double* sq     = (double*)alloc((size_t)NB * NN * 8);
    double* psum   = (double*)alloc((size_t)NB * 8 * NN * 8);
    double* sel    = (double*)alloc((size_t)NB * NN * 8);
    double* R2v    = (double*)alloc((size_t)NB * 8);
    int* samplesN  = (int*)alloc((size_t)NB * NN * 4);
    int* neighborN = (int*)alloc((size_t)NB * NN * 4);
    int* ssum      = (int*)alloc((size_t)NB * 4);
    float* deg     = (float*)alloc((size_t)NN * 4);
    float* keepf   = (float*)alloc((size_t)NB * NN * 4);
    off = (off + 255) & ~(size_t)255;
    size_t rem = (ws_size > off) ? (ws_size - off) : 0;
    int chunk = (int)(rem / ((size_t)NN * NN * 8));
    if (chunk > NB) chunk = NB;
    if (chunk < 1) chunk = 1;
    double* d2buf = (double*)(w + off);

    hipMemsetAsync(ssum, 0, NB * 4, stream);
    k_stats<<<NB * NF / 4, 256, 0, stream>>>(data, meanv, invv);
    k_sq1<<<dim3(NB * 4, 8), 256, 0, stream>>>(data, meanv, invv, psum);
    k_sq2<<<NB * NN / 256, 256, 0, stream>>>(psum, sq);
    k_deg<<<NN / 4, 256, 0, stream>>>(adj, deg);

    for (int b0 = 0; b0 < NB; b0 += chunk) {
        int c = (NB - b0 < chunk) ? (NB - b0) : chunk;
        dim3 gg(136, 1, c);
        k_gemm_sym<<<gg, 256, 0, stream>>>(data, meanv, invv, sq, d2buf, b0);
        k_select<<<c * NN / 4, 256, 0, stream>>>(d2buf, sel, b0);
        k_R<<<c, 256, 0, stream>>>(sel, R2v, b0);
        k_counts<<<c * NN, 256, 0, stream>>>(d2buf, adj, R2v, samplesN, neighborN, ssum, b0);
    }

    k_rank<<<NB, 1024, 0, stream>>>(samplesN, neighborN, ssum, deg, pptr, keepf, outScore);
    k_apply<<<(NB * NF * NN) / (256 * 4), 256, 0, stream>>>(data, keepf, out);
}